// Round 3
// baseline (1669.839 us; speedup 1.0000x reference)
//
#include <hip/hip_runtime.h>

typedef float f32x4 __attribute__((ext_vector_type(4)));
typedef __bf16 bf16x8 __attribute__((ext_vector_type(8)));

#define NSTAGE 20
#define TSEQ   2048
#define NST    128
#define NP2    256
#define NCLS   202

static __device__ __forceinline__ unsigned short f2b(float f) {
  return __builtin_bit_cast(unsigned short, (__bf16)f);
}
static __device__ __forceinline__ float u2f(unsigned u) {
  return __builtin_bit_cast(float, u);
}

// ---------------------------------------------------------------------------
// Kernel 1: convert weights to bf16 + zero look-back flags.
//  Wp   [64][2048]  = (g0 ⊙ W_embed)^T   (LN gain folded into the GEMM)
//  Bws  [20][256][64]: row n'=2n+p holds B_{re/im}[s][n][k] along k
//  Cws  [20][64][256]: row d holds (C_re[s][d][n], -C_im[s][d][n]) interleaved
//  Wclst[208][64]   = W_cls^T, rows >=202 zero
//  flags[8*128] = 0
// ---------------------------------------------------------------------------
__global__ void lru_convert_kernel(const float* __restrict__ Wemb,
                                   const float* __restrict__ g0,
                                   const float* __restrict__ Bre, const float* __restrict__ Bim,
                                   const float* __restrict__ Cre, const float* __restrict__ Cim,
                                   const float* __restrict__ Wcls,
                                   unsigned short* __restrict__ Wp,
                                   unsigned short* __restrict__ Bws,
                                   unsigned short* __restrict__ Cws,
                                   unsigned short* __restrict__ Wclst,
                                   unsigned* __restrict__ flags)
{
  const int NWT = 64 * 2048;          // 131072
  const int NB  = NSTAGE * NP2 * 64;  // 327680
  const int NC  = NSTAGE * 64 * NP2;  // 327680
  const int NWC = 208 * 64;           // 13312
  int idx = blockIdx.x * 256 + threadIdx.x;
  if (idx < NWT) {
    int d = idx >> 11, k = idx & 2047;
    Wp[idx] = f2b(g0[k] * Wemb[k * 64 + d]);
  } else if (idx < NWT + NB) {
    int r = idx - NWT;
    int s = r / (NP2 * 64); int r2 = r % (NP2 * 64);
    int np = r2 >> 6, k = r2 & 63;
    int n = np >> 1, p = np & 1;
    float v = p ? Bim[(s * NST + n) * 64 + k] : Bre[(s * NST + n) * 64 + k];
    Bws[r] = f2b(v);
  } else if (idx < NWT + NB + NC) {
    int r = idx - NWT - NB;
    int s = r / (64 * NP2); int r2 = r % (64 * NP2);
    int d = r2 >> 8, np = r2 & 255;
    int n = np >> 1, p = np & 1;
    float v = p ? -Cim[(s * 64 + d) * NST + n] : Cre[(s * 64 + d) * NST + n];
    Cws[r] = f2b(v);
  } else if (idx < NWT + NB + NC + NWC) {
    int r = idx - NWT - NB - NC;
    int cls = r >> 6, k = r & 63;
    Wclst[r] = (cls < NCLS) ? f2b(Wcls[k * NCLS + cls]) : (unsigned short)0;
  } else if (idx < NWT + NB + NC + NWC + 1024) {
    flags[idx - (NWT + NB + NC + NWC)] = 0u;
  }
}

// ---------------------------------------------------------------------------
// Kernel 1b: rank-1 LN-fold vectors.
//  gsW[d] = sum_k g0[k]*W[k][d]     (for the -rs*mu correction)
//  bWe[d] = sum_k b0[k]*W[k][d] + b_embed[d]
// ---------------------------------------------------------------------------
__global__ void lru_embaux_kernel(const float* __restrict__ Wemb,
                                  const float* __restrict__ g0,
                                  const float* __restrict__ b0,
                                  const float* __restrict__ bemb,
                                  float* __restrict__ gsW,
                                  float* __restrict__ bWe)
{
  __shared__ float rg[256], rb[256];
  const int d = blockIdx.x;
  const int tid = threadIdx.x;
  float sg = 0.f, sb = 0.f;
  for (int k = tid; k < 2048; k += 256) {
    float wv = Wemb[k * 64 + d];
    sg += g0[k] * wv;
    sb += b0[k] * wv;
  }
  rg[tid] = sg; rb[tid] = sb;
  __syncthreads();
  for (int s = 128; s > 0; s >>= 1) {
    if (tid < s) { rg[tid] += rg[tid + s]; rb[tid] += rb[tid + s]; }
    __syncthreads();
  }
  if (tid == 0) { gsW[d] = rg[0]; bWe[d] = rb[0] + bemb[d]; }
}

// ---------------------------------------------------------------------------
// Kernel 2: single-pass LN0-fused embed GEMM. x read ONCE.
// 1024 blocks x 256 threads; block = (batch, 16-token chunk).
// h0[t][d] = rs_t*(x_t @ Wp_d) - rs_t*mu_t*gsW[d] + bWe[d]
// ---------------------------------------------------------------------------
__launch_bounds__(256, 4)
__global__ void lru_embed_kernel(const float* __restrict__ x,
                                 const unsigned short* __restrict__ Wp,
                                 const float* __restrict__ gsW,
                                 const float* __restrict__ bWe,
                                 float* __restrict__ h0)
{
  __shared__ __align__(16) unsigned short As[16 * 68];  // pitch 68 bf16 = 136 B
  __shared__ float mu_s[16], rs_s[16];

  const int tid = threadIdx.x;
  const int b = blockIdx.x >> 7;
  const int t0 = (blockIdx.x & 127) * 16;
  const int w = tid >> 6, lane = tid & 63;
  const int cl = lane & 15, q = lane >> 4;
  const int st = tid >> 4;            // staging token 0..15
  const int k4 = (tid & 15) * 4;      // staging k offset

  const float* xrow = x + ((size_t)(b * TSEQ + t0 + st)) * 2048 + k4;
  float4 cur = *(const float4*)xrow;
  float4 nxt;
  float sum = 0.f, sq = 0.f;
  f32x4 acc = {0.f, 0.f, 0.f, 0.f};

  for (int kc = 0; kc < 32; ++kc) {
    // stage cur to LDS (bf16) + accumulate raw-x stats
    sum += cur.x + cur.y + cur.z + cur.w;
    sq  += cur.x * cur.x + cur.y * cur.y + cur.z * cur.z + cur.w * cur.w;
    {
      uint2 u;
      u.x = (unsigned)f2b(cur.x) | ((unsigned)f2b(cur.y) << 16);
      u.y = (unsigned)f2b(cur.z) | ((unsigned)f2b(cur.w) << 16);
      *(uint2*)((char*)As + st * 136 + k4 * 2) = u;
    }
    __syncthreads();
    if (kc < 31) nxt = *(const float4*)(xrow + (kc + 1) * 64);
    {
      bf16x8 a0 = *(const bf16x8*)((const char*)As + cl * 136 + q * 16);
      bf16x8 a1 = *(const bf16x8*)((const char*)As + cl * 136 + 64 + q * 16);
      const unsigned short* wrow = Wp + ((size_t)(w * 16 + cl)) * 2048 + kc * 64 + q * 8;
      bf16x8 w0 = *(const bf16x8*)wrow;
      bf16x8 w1 = *(const bf16x8*)(wrow + 32);
      acc = __builtin_amdgcn_mfma_f32_16x16x32_bf16(a0, w0, acc, 0, 0, 0);
      acc = __builtin_amdgcn_mfma_f32_16x16x32_bf16(a1, w1, acc, 0, 0, 0);
    }
    __syncthreads();
    cur = nxt;
  }

  // stats: reduce over the 16 lanes covering each token
  sum += __shfl_xor(sum, 1); sq += __shfl_xor(sq, 1);
  sum += __shfl_xor(sum, 2); sq += __shfl_xor(sq, 2);
  sum += __shfl_xor(sum, 4); sq += __shfl_xor(sq, 4);
  sum += __shfl_xor(sum, 8); sq += __shfl_xor(sq, 8);
  if ((tid & 15) == 0) {
    float mu = sum * (1.f / 2048.f);
    float var = sq * (1.f / 2048.f) - mu * mu;
    mu_s[st] = mu;
    rs_s[st] = rsqrtf(var + 1e-5f);
  }
  __syncthreads();

  // epilogue: wave w -> d-tile w; C layout col=cl (d), row=q*4+r (token)
  {
    int d = w * 16 + cl;
    float gs = gsW[d], bw = bWe[d];
    #pragma unroll
    for (int r = 0; r < 4; ++r) {
      int t = q * 4 + r;
      float rs = rs_s[t], mu = mu_s[t];
      h0[((size_t)(b * TSEQ + t0 + t)) * 64 + d] = rs * acc[r] - rs * mu * gs + bw;
    }
  }
}

// ---------------------------------------------------------------------------
// Kernel 3 (per stage): LN -> B-proj MFMA -> local scan -> carry publish
// (device-scope) -> poll lower-chunk flags (decoupled look-back) ->
// lambda^16-weighted prefix -> C-proj -> h update (or classifier on last).
// Block = (batch b, 16-token chunk c); 1024 blocks, 4/CU co-resident.
// ---------------------------------------------------------------------------
__launch_bounds__(256, 4)
__global__ void lru_stage_kernel(float* __restrict__ h0,
                                 float* __restrict__ carr,
                                 unsigned* __restrict__ flags,
                                 const unsigned short* __restrict__ Bws,
                                 const unsigned short* __restrict__ Cws,
                                 const float* __restrict__ lng,
                                 const float* __restrict__ lnb,
                                 const float* __restrict__ nulog,
                                 const float* __restrict__ thlog,
                                 const float* __restrict__ gmlog,
                                 const float* __restrict__ dskip,
                                 int s, int last,
                                 const unsigned short* __restrict__ Wclst,
                                 const float* __restrict__ bcls,
                                 float* __restrict__ out)
{
  __shared__ __align__(16) float hsm[16][68];
  __shared__ __align__(16) float zsm[16][68];
  __shared__ __align__(16) unsigned short zb[16][72];
  __shared__ __align__(16) float ucat[16][264];
  __shared__ __align__(16) unsigned short hcb[16][264];

  const int tid = threadIdx.x;
  const int b = blockIdx.x >> 7;
  const int c = blockIdx.x & 127;
  const int t0 = c * 16;

  const int tg = tid >> 4;
  const int g  = tid & 15;
  const int w  = tid >> 6;
  const int lane = tid & 63;
  const int cl = lane & 15;
  const int q  = lane >> 4;

  // ---- load h tile + LayerNorm
  {
    float4 hv = *(const float4*)&h0[((size_t)(b * TSEQ + t0 + tg)) * 64 + g * 4];
    hsm[tg][g * 4 + 0] = hv.x; hsm[tg][g * 4 + 1] = hv.y;
    hsm[tg][g * 4 + 2] = hv.z; hsm[tg][g * 4 + 3] = hv.w;
    float sum = hv.x + hv.y + hv.z + hv.w;
    sum += __shfl_xor(sum, 1); sum += __shfl_xor(sum, 2);
    sum += __shfl_xor(sum, 4); sum += __shfl_xor(sum, 8);
    float mu = sum * (1.f / 64.f);
    float d0 = hv.x - mu, d1 = hv.y - mu, d2 = hv.z - mu, d3 = hv.w - mu;
    float sqv = d0 * d0 + d1 * d1 + d2 * d2 + d3 * d3;
    sqv += __shfl_xor(sqv, 1); sqv += __shfl_xor(sqv, 2);
    sqv += __shfl_xor(sqv, 4); sqv += __shfl_xor(sqv, 8);
    float rs = rsqrtf(sqv * (1.f / 64.f) + 1e-5f);
    float4 gv = *(const float4*)&lng[s * 64 + g * 4];
    float4 bv = *(const float4*)&lnb[s * 64 + g * 4];
    float z0 = d0 * rs * gv.x + bv.x;
    float z1 = d1 * rs * gv.y + bv.y;
    float z2 = d2 * rs * gv.z + bv.z;
    float z3 = d3 * rs * gv.w + bv.w;
    zsm[tg][g * 4 + 0] = z0; zsm[tg][g * 4 + 1] = z1;
    zsm[tg][g * 4 + 2] = z2; zsm[tg][g * 4 + 3] = z3;
    *(unsigned*)&zb[tg][g * 4]     = (unsigned)f2b(z0) | ((unsigned)f2b(z1) << 16);
    *(unsigned*)&zb[tg][g * 4 + 2] = (unsigned)f2b(z2) | ((unsigned)f2b(z3) << 16);
  }
  __syncthreads();

  // ---- U = Z * B^T scaled by gamma (MFMA)
  {
    bf16x8 a0 = *(const bf16x8*)((const char*)&zb[0][0] + cl * 144 + q * 16);
    bf16x8 a1 = *(const bf16x8*)((const char*)&zb[0][0] + cl * 144 + 64 + q * 16);
    const unsigned short* bb = Bws + (size_t)s * NP2 * 64;
    for (int ti = 0; ti < 4; ++ti) {
      int np0 = (w * 4 + ti) * 16;
      const unsigned short* bp = bb + (np0 + cl) * 64 + q * 8;
      bf16x8 b0 = *(const bf16x8*)bp;
      bf16x8 b1 = *(const bf16x8*)(bp + 32);
      f32x4 acc = {0.f, 0.f, 0.f, 0.f};
      acc = __builtin_amdgcn_mfma_f32_16x16x32_bf16(a0, b0, acc, 0, 0, 0);
      acc = __builtin_amdgcn_mfma_f32_16x16x32_bf16(a1, b1, acc, 0, 0, 0);
      int np = np0 + cl;
      float gam = __expf(gmlog[s * NST + (np >> 1)]);
      ucat[q * 4 + 0][np] = acc[0] * gam;
      ucat[q * 4 + 1][np] = acc[1] * gam;
      ucat[q * 4 + 2][np] = acc[2] * gam;
      ucat[q * 4 + 3][np] = acc[3] * gam;
    }
  }
  __syncthreads();

  // ---- local scan + carry publish
  float lamr = 0.f, lami = 0.f, l16r = 0.f, l16i = 0.f;
  if (tid < NST) {
    int n = tid;
    float mag = __expf(-__expf(nulog[s * NST + n]));
    float th  = __expf(thlog[s * NST + n]);
    lamr = mag * __cosf(th);
    lami = mag * __sinf(th);
    float hr = 0.f, hi = 0.f;
    #pragma unroll
    for (int t = 0; t < 16; ++t) {
      float ur = ucat[t][2 * n], ui = ucat[t][2 * n + 1];
      float nr = fmaf(lamr, hr, fmaf(-lami, hi, ur));
      float ni = fmaf(lamr, hi, fmaf(lami, hr, ui));
      hr = nr; hi = ni;
      ucat[t][2 * n] = hr; ucat[t][2 * n + 1] = hi;
    }
    float ar = lamr, ai = lami;
    #pragma unroll
    for (int it = 0; it < 4; ++it) {
      float nr = ar * ar - ai * ai;
      float ni = 2.f * ar * ai;
      ar = nr; ai = ni;
    }
    l16r = ar; l16i = ai;
    // device-scope publish (goes to the coherence point; cross-XCD safe)
    unsigned long long uv = ((unsigned long long)__builtin_bit_cast(unsigned, hi) << 32)
                          |  (unsigned long long)__builtin_bit_cast(unsigned, hr);
    __hip_atomic_store((unsigned long long*)(carr + ((size_t)(b * 128 + c)) * 256 + n * 2),
                       uv, __ATOMIC_RELAXED, __HIP_MEMORY_SCOPE_AGENT);
  }
  __syncthreads();  // compiler drains vmcnt before barrier -> carries performed

  if (tid == 0)
    __hip_atomic_store(&flags[b * 128 + c], (unsigned)(s + 1),
                       __ATOMIC_RELEASE, __HIP_MEMORY_SCOPE_AGENT);
  // decoupled look-back: poll only LOWER chunk ids (dispatch-order safe)
  if (tid < c) {
    while (__hip_atomic_load(&flags[b * 128 + tid], __ATOMIC_ACQUIRE,
                             __HIP_MEMORY_SCOPE_AGENT) < (unsigned)(s + 1)) {}
  }
  __syncthreads();

  // ---- lambda^16-weighted prefix over earlier chunks, apply -> hcb (bf16)
  if (tid < NST) {
    int n = tid;
    float Pr = 0.f, Pi = 0.f;
    const unsigned long long* cb =
        (const unsigned long long*)(carr + ((size_t)b * 128) * 256 + n * 2);
    for (int j = 0; j < c; ++j) {
      unsigned long long uv = __hip_atomic_load(&cb[j * 128], __ATOMIC_RELAXED,
                                                __HIP_MEMORY_SCOPE_AGENT);
      float cr = u2f((unsigned)uv);
      float ci = u2f((unsigned)(uv >> 32));
      float nr = fmaf(l16r, Pr, fmaf(-l16i, Pi, cr));
      float ni = fmaf(l16r, Pi, fmaf(l16i, Pr, ci));
      Pr = nr; Pi = ni;
    }
    float mr = lamr, mi = lami;
    #pragma unroll
    for (int t = 0; t < 16; ++t) {
      float hgr = ucat[t][2 * n]     + mr * Pr - mi * Pi;
      float hgi = ucat[t][2 * n + 1] + mr * Pi + mi * Pr;
      *(unsigned*)&hcb[t][2 * n] = (unsigned)f2b(hgr) | ((unsigned)f2b(hgi) << 16);
      float nmr = mr * lamr - mi * lami;
      float nmi = mr * lami + mi * lamr;
      mr = nmr; mi = nmi;
    }
  }
  __syncthreads();

  // ---- Y = Hcat * Cc (MFMA, K=256); h += y + Dskip*z
  {
    int d0 = w * 16;
    const unsigned short* cp = Cws + ((size_t)s * 64 + d0 + cl) * NP2 + q * 8;
    f32x4 acc = {0.f, 0.f, 0.f, 0.f};
    #pragma unroll
    for (int ks = 0; ks < 8; ++ks) {
      bf16x8 a  = *(const bf16x8*)((const char*)&hcb[0][0] + cl * 528 + ks * 64 + q * 16);
      bf16x8 cc = *(const bf16x8*)(cp + ks * 32);
      acc = __builtin_amdgcn_mfma_f32_16x16x32_bf16(a, cc, acc, 0, 0, 0);
    }
    int d = d0 + cl;
    float dk = dskip[s * 64 + d];
    #pragma unroll
    for (int r = 0; r < 4; ++r) {
      int t = q * 4 + r;
      hsm[t][d] = hsm[t][d] + acc[r] + dk * zsm[t][d];
    }
  }
  __syncthreads();

  if (!last) {
    float4 hv;
    hv.x = hsm[tg][g * 4 + 0]; hv.y = hsm[tg][g * 4 + 1];
    hv.z = hsm[tg][g * 4 + 2]; hv.w = hsm[tg][g * 4 + 3];
    *(float4*)&h0[((size_t)(b * TSEQ + t0 + tg)) * 64 + g * 4] = hv;
  } else {
    {
      float4 hv;
      hv.x = hsm[tg][g * 4 + 0]; hv.y = hsm[tg][g * 4 + 1];
      hv.z = hsm[tg][g * 4 + 2]; hv.w = hsm[tg][g * 4 + 3];
      *(unsigned*)&zb[tg][g * 4]     = (unsigned)f2b(hv.x) | ((unsigned)f2b(hv.y) << 16);
      *(unsigned*)&zb[tg][g * 4 + 2] = (unsigned)f2b(hv.z) | ((unsigned)f2b(hv.w) << 16);
    }
    __syncthreads();
    bf16x8 a0 = *(const bf16x8*)((const char*)&zb[0][0] + cl * 144 + q * 16);
    bf16x8 a1 = *(const bf16x8*)((const char*)&zb[0][0] + cl * 144 + 64 + q * 16);
    for (int ti = w; ti < 13; ti += 4) {
      int cls0 = ti * 16;
      const unsigned short* wp = Wclst + (cls0 + cl) * 64 + q * 8;
      bf16x8 b0 = *(const bf16x8*)wp;
      bf16x8 b1 = *(const bf16x8*)(wp + 32);
      f32x4 acc = {0.f, 0.f, 0.f, 0.f};
      acc = __builtin_amdgcn_mfma_f32_16x16x32_bf16(a0, b0, acc, 0, 0, 0);
      acc = __builtin_amdgcn_mfma_f32_16x16x32_bf16(a1, b1, acc, 0, 0, 0);
      int cls = cls0 + cl;
      if (cls < NCLS) {
        float bc = bcls[cls];
        #pragma unroll
        for (int r = 0; r < 4; ++r) {
          int t = q * 4 + r;
          out[((size_t)(b * TSEQ + t0 + t)) * NCLS + cls] = acc[r] + bc;
        }
      }
    }
  }
}

// ---------------------------------------------------------------------------
extern "C" void kernel_launch(void* const* d_in, const int* in_sizes, int n_in,
                              void* d_out, int out_size, void* d_ws, size_t ws_size,
                              hipStream_t stream) {
  (void)in_sizes; (void)n_in; (void)out_size; (void)ws_size;
  const float* x     = (const float*)d_in[0];
  const float* ln0g  = (const float*)d_in[1];
  const float* ln0b  = (const float*)d_in[2];
  const float* Wemb  = (const float*)d_in[3];
  const float* bemb  = (const float*)d_in[4];
  const float* lng   = (const float*)d_in[5];
  const float* lnb   = (const float*)d_in[6];
  const float* nulog = (const float*)d_in[7];
  const float* thlog = (const float*)d_in[8];
  const float* gmlog = (const float*)d_in[9];
  const float* Bre   = (const float*)d_in[10];
  const float* Bim   = (const float*)d_in[11];
  const float* Cre   = (const float*)d_in[12];
  const float* Cim   = (const float*)d_in[13];
  const float* dskip = (const float*)d_in[14];
  const float* Wcls  = (const float*)d_in[15];
  const float* bcls  = (const float*)d_in[16];
  float* out = (float*)d_out;

  char* ws = (char*)d_ws;
  // ws layout (bytes):
  //  h0    @0        : 16384*64*4 = 4194304
  //  carr  @4194304  : 8*128*256*4 = 1048576   (end 5242880)
  //  flags @5242880  : 1024*4      = 4096      (end 5246976)
  //  gsW   @5246976  : 64*4        = 256
  //  bWe   @5247232  : 64*4        = 256       (end 5247488)
  //  Bws   @5248000  : 655360                  (end 5903360)
  //  Cws   @5903360  : 655360                  (end 6558720)
  //  Wp    @6558720  : 262144                  (end 6820864)
  //  Wclst @6820864  : 26624                   (end 6847488)
  float* h0            = (float*)(ws + 0);
  float* carr          = (float*)(ws + 4194304);
  unsigned* flags      = (unsigned*)(ws + 5242880);
  float* gsW           = (float*)(ws + 5246976);
  float* bWe           = (float*)(ws + 5247232);
  unsigned short* Bws  = (unsigned short*)(ws + 5248000);
  unsigned short* Cws  = (unsigned short*)(ws + 5903360);
  unsigned short* Wp   = (unsigned short*)(ws + 6558720);
  unsigned short* Wcl  = (unsigned short*)(ws + 6820864);

  lru_convert_kernel<<<3128, 256, 0, stream>>>(Wemb, ln0g, Bre, Bim, Cre, Cim,
                                               Wcls, Wp, Bws, Cws, Wcl, flags);
  lru_embaux_kernel<<<64, 256, 0, stream>>>(Wemb, ln0g, ln0b, bemb, gsW, bWe);
  lru_embed_kernel<<<1024, 256, 0, stream>>>(x, Wp, gsW, bWe, h0);

  for (int s = 0; s < NSTAGE; ++s) {
    lru_stage_kernel<<<1024, 256, 0, stream>>>(h0, carr, flags, Bws, Cws,
                                               lng, lnb, nulog, thlog, gmlog,
                                               dskip, s, (s == NSTAGE - 1) ? 1 : 0,
                                               Wcl, bcls, out);
  }
}